// Round 3
// baseline (462.352 us; speedup 1.0000x reference)
//
#include <hip/hip_runtime.h>
#include <math.h>

#define NB 8
#define NN 10000
#define NE 160000
#define FD 64
#define BN (NB * NN)              // 80000
#define TOTE (NB * NE)            // 1280000
#define NBLK ((BN + 255) / 256)   // 313
#define EPB 10000                 // edges per pass-A block
#define BPG (NE / EPB)            // 16 blocks per graph
#define NPA (NB * BPG)            // 128 pass-A blocks

// ---------- pass A: LDS histogram count + local rank (no global atomics) ----------
__global__ __launch_bounds__(256) void k_count_lds(const int* __restrict__ ei,
                                                   int* __restrict__ rank,
                                                   int* __restrict__ cnt) {
    __shared__ int hist[NN];  // 40 KB
    for (int i = threadIdx.x; i < NN; i += 256) hist[i] = 0;
    __syncthreads();
    int g = blockIdx.x >> 4;        // BPG = 16
    int j = blockIdx.x & 15;
    int base = g * NE + j * EPB;
    for (int i = threadIdx.x; i < EPB; i += 256) {
        int e = base + i;
        int r = ei[2 * e];          // local node id within graph
        rank[e] = atomicAdd(&hist[r], 1);
    }
    __syncthreads();
    int* cp = cnt + (size_t)blockIdx.x * NN;
    for (int i = threadIdx.x; i < NN; i += 256) cp[i] = hist[i];
}

// ---------- pass B: per-row prefix over the 16 block-counts -> deg, dinv, blocksum ----------
__global__ __launch_bounds__(256) void k_prefix(int* __restrict__ cnt,
                                                int* __restrict__ deg,
                                                float* __restrict__ dinv,
                                                int* __restrict__ blocksum) {
    __shared__ int wsum[4];
    int i = blockIdx.x * 256 + threadIdx.x;
    int lane = threadIdx.x & 63;
    int wv = threadIdx.x >> 6;
    int d = 0;
    if (i < BN) {
        int g = i / NN;
        int r = i - g * NN;
        int* cp = cnt + ((size_t)g * BPG) * NN + r;
        int run = 0;
#pragma unroll
        for (int j = 0; j < BPG; j++) {
            int v = cp[(size_t)j * NN];
            cp[(size_t)j * NN] = run;   // exclusive prefix across blocks
            run += v;
        }
        d = run;
        deg[i] = d;
        dinv[i] = (d > 0) ? (1.0f / sqrtf((float)d)) : 0.0f;
    }
    int s = d;
#pragma unroll
    for (int off = 32; off > 0; off >>= 1) s += __shfl_down(s, off);
    if (lane == 0) wsum[wv] = s;
    __syncthreads();
    if (threadIdx.x == 0)
        blocksum[blockIdx.x] = wsum[0] + wsum[1] + wsum[2] + wsum[3];
}

// ---------- 1-wave exclusive scan of 313 block sums ----------
__global__ __launch_bounds__(64) void k_scanblk(const int* __restrict__ blocksum,
                                                int* __restrict__ blockoff,
                                                int* __restrict__ row_start) {
    int lane = threadIdx.x;
    int carry = 0;
    for (int base = 0; base < NBLK; base += 64) {
        int i = base + lane;
        int v = (i < NBLK) ? blocksum[i] : 0;
        int x = v;
#pragma unroll
        for (int off = 1; off < 64; off <<= 1) {
            int y = __shfl_up(x, off);
            if (lane >= off) x += y;
        }
        if (i < NBLK) blockoff[i] = carry + (x - v);
        carry += __shfl(x, 63);
    }
    if (lane == 0) row_start[BN] = carry;
}

// ---------- per-block rescan -> row_start ----------
__global__ __launch_bounds__(256) void k_scan2(const int* __restrict__ deg,
                                               const int* __restrict__ blockoff,
                                               int* __restrict__ row_start) {
    __shared__ int wsum[4];
    int i = blockIdx.x * 256 + threadIdx.x;
    int lane = threadIdx.x & 63;
    int wv = threadIdx.x >> 6;
    int v = (i < BN) ? deg[i] : 0;
    int x = v;
#pragma unroll
    for (int off = 1; off < 64; off <<= 1) {
        int y = __shfl_up(x, off);
        if (lane >= off) x += y;
    }
    if (lane == 63) wsum[wv] = x;
    __syncthreads();
    int add = 0;
    for (int w = 0; w < wv; w++) add += wsum[w];
    if (i < BN) row_start[i] = blockoff[blockIdx.x] + add + (x - v);
}

// ---------- fill CSR: edge_cn[pos] = {col, norm} (atomic-free) ----------
__global__ __launch_bounds__(256) void k_fill(const int* __restrict__ ei,
                                              const int* __restrict__ row_start,
                                              const int* __restrict__ rank,
                                              const int* __restrict__ cnt,
                                              const float* __restrict__ dinv,
                                              int2* __restrict__ edge_cn) {
    int e = blockIdx.x * 256 + threadIdx.x;
    if (e >= TOTE) return;
    int g = e / NE;
    int rem = e - g * NE;
    int j = rem / EPB;
    int rl = ei[2 * e];
    int cl = ei[2 * e + 1];
    int r = g * NN + rl;
    int c = g * NN + cl;
    int pos = row_start[r] + cnt[((size_t)(g * BPG + j)) * NN + rl] + rank[e];
    float nm = dinv[r] * dinv[c];
    edge_cn[pos] = make_int2(c, __float_as_int(nm));
}

// ---------- linear: t[n][:] = act(h[n]) @ W^T + b ; 2 rows/thread ----------
template <int RELU>
__global__ __launch_bounds__(128) void k_linear(const float* __restrict__ hin,
                                                const float* __restrict__ W,
                                                const float* __restrict__ bias,
                                                float* __restrict__ tout) {
    __shared__ __align__(16) float Wsh[FD * FD];  // row-major, as stored
    __shared__ float bsh[FD];
    for (int idx = threadIdx.x; idx < FD * FD; idx += 128) Wsh[idx] = W[idx];
    if (threadIdx.x < FD) bsh[threadIdx.x] = bias[threadIdx.x];
    __syncthreads();

    int n0 = blockIdx.x * 256 + threadIdx.x;   // rows n0 and n0+128
    int n1 = n0 + 128;
    bool v1 = n1 < BN;          // n0 always < BN (grid sized exactly)
    int n1s = v1 ? n1 : n0;     // safe address

    float4 h0[16], h1[16];
    const float4* hp0 = (const float4*)(hin + (size_t)n0 * FD);
    const float4* hp1 = (const float4*)(hin + (size_t)n1s * FD);
#pragma unroll
    for (int k4 = 0; k4 < 16; k4++) {
        float4 a = hp0[k4];
        float4 b = hp1[k4];
        if (RELU) {
            a.x = fmaxf(a.x, 0.f); a.y = fmaxf(a.y, 0.f);
            a.z = fmaxf(a.z, 0.f); a.w = fmaxf(a.w, 0.f);
            b.x = fmaxf(b.x, 0.f); b.y = fmaxf(b.y, 0.f);
            b.z = fmaxf(b.z, 0.f); b.w = fmaxf(b.w, 0.f);
        }
        h0[k4] = a;
        h1[k4] = b;
    }

    float4* op0 = (float4*)(tout + (size_t)n0 * FD);
    float4* op1 = (float4*)(tout + (size_t)n1 * FD);
#pragma unroll
    for (int j4 = 0; j4 < 16; j4++) {
        float s0[4], s1[4];
#pragma unroll
        for (int jj = 0; jj < 4; jj++) {
            float b = bsh[j4 * 4 + jj];
            s0[jj] = b;
            s1[jj] = b;
        }
#pragma unroll
        for (int k4 = 0; k4 < 16; k4++) {
#pragma unroll
            for (int jj = 0; jj < 4; jj++) {
                float4 w = ((const float4*)&Wsh[(j4 * 4 + jj) * FD])[k4];
                s0[jj] += h0[k4].x * w.x + h0[k4].y * w.y + h0[k4].z * w.z + h0[k4].w * w.w;
                s1[jj] += h1[k4].x * w.x + h1[k4].y * w.y + h1[k4].z * w.z + h1[k4].w * w.w;
            }
        }
        op0[j4] = make_float4(s0[0], s0[1], s0[2], s0[3]);
        if (v1) op1[j4] = make_float4(s1[0], s1[1], s1[2], s1[3]);
    }
}

// ---------- aggregate (pull, CSR): 4 edge slots x 4 deep = 16 edges in flight ----------
// lane = eg(2b)*16 + fl(4b): eg = edge slot, fl = float4 feature group
__global__ __launch_bounds__(256) void k_agg(const float* __restrict__ t,
                                             const int* __restrict__ row_start,
                                             const int2* __restrict__ edge_cn,
                                             float* __restrict__ out) {
    int node = (blockIdx.x * 256 + threadIdx.x) >> 6;
    int lane = threadIdx.x & 63;
    if (node >= BN) return;
    int p0 = row_start[node];
    int pe = row_start[node + 1];
    int eg = lane >> 4;
    int fl = lane & 15;
    float4 acc = make_float4(0.f, 0.f, 0.f, 0.f);
    int p = p0 + eg;
    for (; p + 12 < pe; p += 16) {
        int2 cn0 = edge_cn[p];
        int2 cn1 = edge_cn[p + 4];
        int2 cn2 = edge_cn[p + 8];
        int2 cn3 = edge_cn[p + 12];
        float4 t0 = ((const float4*)(t + (size_t)cn0.x * FD))[fl];
        float4 t1 = ((const float4*)(t + (size_t)cn1.x * FD))[fl];
        float4 t2 = ((const float4*)(t + (size_t)cn2.x * FD))[fl];
        float4 t3 = ((const float4*)(t + (size_t)cn3.x * FD))[fl];
        float n0 = __int_as_float(cn0.y), n1 = __int_as_float(cn1.y);
        float n2 = __int_as_float(cn2.y), n3 = __int_as_float(cn3.y);
        acc.x += n0 * t0.x + n1 * t1.x + n2 * t2.x + n3 * t3.x;
        acc.y += n0 * t0.y + n1 * t1.y + n2 * t2.y + n3 * t3.y;
        acc.z += n0 * t0.z + n1 * t1.z + n2 * t2.z + n3 * t3.z;
        acc.w += n0 * t0.w + n1 * t1.w + n2 * t2.w + n3 * t3.w;
    }
    for (; p < pe; p += 4) {
        int2 cn = edge_cn[p];
        float4 tv = ((const float4*)(t + (size_t)cn.x * FD))[fl];
        float nm = __int_as_float(cn.y);
        acc.x += nm * tv.x;
        acc.y += nm * tv.y;
        acc.z += nm * tv.z;
        acc.w += nm * tv.w;
    }
    acc.x += __shfl_down(acc.x, 32); acc.y += __shfl_down(acc.y, 32);
    acc.z += __shfl_down(acc.z, 32); acc.w += __shfl_down(acc.w, 32);
    acc.x += __shfl_down(acc.x, 16); acc.y += __shfl_down(acc.y, 16);
    acc.z += __shfl_down(acc.z, 16); acc.w += __shfl_down(acc.w, 16);
    if (lane < 16) {
        float4* op = (float4*)(out + (size_t)node * FD);
        op[fl] = acc;
    }
}

extern "C" void kernel_launch(void* const* d_in, const int* in_sizes, int n_in,
                              void* d_out, int out_size, void* d_ws, size_t ws_size,
                              hipStream_t stream) {
    const float* x  = (const float*)d_in[0];
    const int*   ei = (const int*)d_in[1];
    const float* W1 = (const float*)d_in[2];
    const float* b1 = (const float*)d_in[3];
    const float* W2 = (const float*)d_in[4];
    const float* b2 = (const float*)d_in[5];
    const float* W3 = (const float*)d_in[6];
    const float* b3 = (const float*)d_in[7];
    float* out = (float*)d_out;

    char* ws = (char*)d_ws;
    size_t off = 0;
    float* t        = (float*)(ws + off); off += (size_t)BN * FD * 4;     // 20.48 MB
    int2*  edge_cn  = (int2*)(ws + off);  off += (size_t)TOTE * 8;        // 10.24 MB
    int*   deg      = (int*)(ws + off);   off += (size_t)BN * 4;
    int*   row_start= (int*)(ws + off);   off += (size_t)(BN + 1) * 4;
    float* dinv     = (float*)(ws + off); off += (size_t)BN * 4;
    int*   blocksum = (int*)(ws + off);   off += (size_t)NBLK * 4;
    int*   blockoff = (int*)(ws + off);   off += (size_t)NBLK * 4;
    // rank (5.12 MB) and cnt (5.12 MB) alias t: both are dead before the
    // first k_linear writes t (stream-ordered after k_fill).
    int*   rank     = (int*)t;
    int*   cnt      = (int*)t + (size_t)TOTE;

    const int eb = (TOTE + 255) / 256;      // 5000
    const int ab = (BN * 64 + 255) / 256;   // 20000

    k_count_lds<<<NPA, 256, 0, stream>>>(ei, rank, cnt);
    k_prefix<<<NBLK, 256, 0, stream>>>(cnt, deg, dinv, blocksum);
    k_scanblk<<<1, 64, 0, stream>>>(blocksum, blockoff, row_start);
    k_scan2<<<NBLK, 256, 0, stream>>>(deg, blockoff, row_start);
    k_fill<<<eb, 256, 0, stream>>>(ei, row_start, rank, cnt, dinv, edge_cn);

    // layer 1: t = x@W1^T + b1 ; h1 = agg(t) -> out
    k_linear<0><<<NBLK, 128, 0, stream>>>(x, W1, b1, t);
    k_agg<<<ab, 256, 0, stream>>>(t, row_start, edge_cn, out);
    // layer 2: t = relu(h1)@W2^T + b2 ; h2 = agg(t) -> out
    k_linear<1><<<NBLK, 128, 0, stream>>>(out, W2, b2, t);
    k_agg<<<ab, 256, 0, stream>>>(t, row_start, edge_cn, out);
    // layer 3: t = relu(h2)@W3^T + b3 ; out = agg(t)
    k_linear<1><<<NBLK, 128, 0, stream>>>(out, W3, b3, t);
    k_agg<<<ab, 256, 0, stream>>>(t, row_start, edge_cn, out);
}

// Round 4
// 337.925 us; speedup vs baseline: 1.3682x; 1.3682x over previous
//
#include <hip/hip_runtime.h>
#include <math.h>

#define NB 8
#define NN 10000
#define NE 160000
#define FD 64
#define BN (NB * NN)              // 80000
#define TOTE (NB * NE)            // 1280000
#define NBLK ((BN + 255) / 256)   // 313
#define EPB 10000                 // edges per pass-A block
#define BPG (NE / EPB)            // 16 blocks per graph
#define NPA (NB * BPG)            // 128 pass-A blocks

// ---------- pass A: LDS histogram count + local rank (no global atomics) ----------
__global__ __launch_bounds__(256) void k_count_lds(const int* __restrict__ ei,
                                                   int* __restrict__ rank,
                                                   int* __restrict__ cnt) {
    __shared__ int hist[NN];  // 40 KB
    for (int i = threadIdx.x; i < NN; i += 256) hist[i] = 0;
    __syncthreads();
    int g = blockIdx.x >> 4;        // BPG = 16
    int j = blockIdx.x & 15;
    int base = g * NE + j * EPB;
    for (int i = threadIdx.x; i < EPB; i += 256) {
        int e = base + i;
        int r = ei[2 * e];          // local node id within graph
        rank[e] = atomicAdd(&hist[r], 1);
    }
    __syncthreads();
    int* cp = cnt + (size_t)blockIdx.x * NN;
    for (int i = threadIdx.x; i < NN; i += 256) cp[i] = hist[i];
}

// ---------- pass B: per-row prefix over the 16 block-counts -> deg, dinv, blocksum ----------
__global__ __launch_bounds__(256) void k_prefix(int* __restrict__ cnt,
                                                int* __restrict__ deg,
                                                float* __restrict__ dinv,
                                                int* __restrict__ blocksum) {
    __shared__ int wsum[4];
    int i = blockIdx.x * 256 + threadIdx.x;
    int lane = threadIdx.x & 63;
    int wv = threadIdx.x >> 6;
    int d = 0;
    if (i < BN) {
        int g = i / NN;
        int r = i - g * NN;
        int* cp = cnt + ((size_t)g * BPG) * NN + r;
        int run = 0;
#pragma unroll
        for (int j = 0; j < BPG; j++) {
            int v = cp[(size_t)j * NN];
            cp[(size_t)j * NN] = run;   // exclusive prefix across blocks
            run += v;
        }
        d = run;
        deg[i] = d;
        dinv[i] = (d > 0) ? (1.0f / sqrtf((float)d)) : 0.0f;
    }
    int s = d;
#pragma unroll
    for (int off = 32; off > 0; off >>= 1) s += __shfl_down(s, off);
    if (lane == 0) wsum[wv] = s;
    __syncthreads();
    if (threadIdx.x == 0)
        blocksum[blockIdx.x] = wsum[0] + wsum[1] + wsum[2] + wsum[3];
}

// ---------- 1-wave exclusive scan of 313 block sums ----------
__global__ __launch_bounds__(64) void k_scanblk(const int* __restrict__ blocksum,
                                                int* __restrict__ blockoff,
                                                int* __restrict__ row_start) {
    int lane = threadIdx.x;
    int carry = 0;
    for (int base = 0; base < NBLK; base += 64) {
        int i = base + lane;
        int v = (i < NBLK) ? blocksum[i] : 0;
        int x = v;
#pragma unroll
        for (int off = 1; off < 64; off <<= 1) {
            int y = __shfl_up(x, off);
            if (lane >= off) x += y;
        }
        if (i < NBLK) blockoff[i] = carry + (x - v);
        carry += __shfl(x, 63);
    }
    if (lane == 0) row_start[BN] = carry;
}

// ---------- per-block rescan -> row_start ----------
__global__ __launch_bounds__(256) void k_scan2(const int* __restrict__ deg,
                                               const int* __restrict__ blockoff,
                                               int* __restrict__ row_start) {
    __shared__ int wsum[4];
    int i = blockIdx.x * 256 + threadIdx.x;
    int lane = threadIdx.x & 63;
    int wv = threadIdx.x >> 6;
    int v = (i < BN) ? deg[i] : 0;
    int x = v;
#pragma unroll
    for (int off = 1; off < 64; off <<= 1) {
        int y = __shfl_up(x, off);
        if (lane >= off) x += y;
    }
    if (lane == 63) wsum[wv] = x;
    __syncthreads();
    int add = 0;
    for (int w = 0; w < wv; w++) add += wsum[w];
    if (i < BN) row_start[i] = blockoff[blockIdx.x] + add + (x - v);
}

// ---------- fill CSR: edge_cn[pos] = {col, norm} (atomic-free) ----------
__global__ __launch_bounds__(256) void k_fill(const int* __restrict__ ei,
                                              const int* __restrict__ row_start,
                                              const int* __restrict__ rank,
                                              const int* __restrict__ cnt,
                                              const float* __restrict__ dinv,
                                              int2* __restrict__ edge_cn) {
    int e = blockIdx.x * 256 + threadIdx.x;
    if (e >= TOTE) return;
    int g = e / NE;
    int rem = e - g * NE;
    int j = rem / EPB;
    int rl = ei[2 * e];
    int cl = ei[2 * e + 1];
    int r = g * NN + rl;
    int c = g * NN + cl;
    int pos = row_start[r] + cnt[((size_t)(g * BPG + j)) * NN + rl] + rank[e];
    float nm = dinv[r] * dinv[c];
    edge_cn[pos] = make_int2(c, __float_as_int(nm));
}

// ---------- linear: t[n][j] = (act(h[n]) @ W^T + b)[j] ----------
// thread-per-row; W transposed in LDS, broadcast float4 reads (conflict-free).
// VALU-bound at ~4096 FMA/thread; VGPR ~110 -> good occupancy. (R2-proven.)
template <int RELU>
__global__ __launch_bounds__(256) void k_linear(const float* __restrict__ hin,
                                                const float* __restrict__ W,
                                                const float* __restrict__ bias,
                                                float* __restrict__ tout) {
    __shared__ __align__(16) float Wt[FD * FD];  // Wt[k*64 + j] = W[j*64 + k]
    __shared__ float bsh[FD];
    for (int idx = threadIdx.x; idx < FD * FD; idx += 256) {
        int j = idx >> 6, k = idx & 63;
        Wt[k * FD + j] = W[idx];
    }
    if (threadIdx.x < FD) bsh[threadIdx.x] = bias[threadIdx.x];
    __syncthreads();

    int n = blockIdx.x * 256 + threadIdx.x;
    if (n >= BN) return;

    float acc[FD];
#pragma unroll
    for (int j = 0; j < FD; j++) acc[j] = bsh[j];

    const float4* hp = (const float4*)(hin + (size_t)n * FD);
#pragma unroll
    for (int k4 = 0; k4 < 16; k4++) {
        float4 hv = hp[k4];
        if (RELU) {
            hv.x = fmaxf(hv.x, 0.f);
            hv.y = fmaxf(hv.y, 0.f);
            hv.z = fmaxf(hv.z, 0.f);
            hv.w = fmaxf(hv.w, 0.f);
        }
        float hk[4] = {hv.x, hv.y, hv.z, hv.w};
#pragma unroll
        for (int kk = 0; kk < 4; kk++) {
            const float4* wr = (const float4*)(&Wt[(k4 * 4 + kk) * FD]);
            float h = hk[kk];
#pragma unroll
            for (int j4 = 0; j4 < 16; j4++) {
                float4 w = wr[j4];
                acc[4 * j4 + 0] += h * w.x;
                acc[4 * j4 + 1] += h * w.y;
                acc[4 * j4 + 2] += h * w.z;
                acc[4 * j4 + 3] += h * w.w;
            }
        }
    }
    float4* op = (float4*)(tout + (size_t)n * FD);
#pragma unroll
    for (int j4 = 0; j4 < 16; j4++)
        op[j4] = make_float4(acc[4 * j4], acc[4 * j4 + 1], acc[4 * j4 + 2], acc[4 * j4 + 3]);
}

// ---------- aggregate (pull, CSR): 4 edge slots x 4 deep = 16 edges in flight ----------
// lane = eg(2b)*16 + fl(4b): eg = edge slot, fl = float4 feature group
__global__ __launch_bounds__(256) void k_agg(const float* __restrict__ t,
                                             const int* __restrict__ row_start,
                                             const int2* __restrict__ edge_cn,
                                             float* __restrict__ out) {
    int node = (blockIdx.x * 256 + threadIdx.x) >> 6;
    int lane = threadIdx.x & 63;
    if (node >= BN) return;
    int p0 = row_start[node];
    int pe = row_start[node + 1];
    int eg = lane >> 4;
    int fl = lane & 15;
    float4 acc = make_float4(0.f, 0.f, 0.f, 0.f);
    int p = p0 + eg;
    for (; p + 12 < pe; p += 16) {
        int2 cn0 = edge_cn[p];
        int2 cn1 = edge_cn[p + 4];
        int2 cn2 = edge_cn[p + 8];
        int2 cn3 = edge_cn[p + 12];
        float4 t0 = ((const float4*)(t + (size_t)cn0.x * FD))[fl];
        float4 t1 = ((const float4*)(t + (size_t)cn1.x * FD))[fl];
        float4 t2 = ((const float4*)(t + (size_t)cn2.x * FD))[fl];
        float4 t3 = ((const float4*)(t + (size_t)cn3.x * FD))[fl];
        float n0 = __int_as_float(cn0.y), n1 = __int_as_float(cn1.y);
        float n2 = __int_as_float(cn2.y), n3 = __int_as_float(cn3.y);
        acc.x += n0 * t0.x + n1 * t1.x + n2 * t2.x + n3 * t3.x;
        acc.y += n0 * t0.y + n1 * t1.y + n2 * t2.y + n3 * t3.y;
        acc.z += n0 * t0.z + n1 * t1.z + n2 * t2.z + n3 * t3.z;
        acc.w += n0 * t0.w + n1 * t1.w + n2 * t2.w + n3 * t3.w;
    }
    for (; p < pe; p += 4) {
        int2 cn = edge_cn[p];
        float4 tv = ((const float4*)(t + (size_t)cn.x * FD))[fl];
        float nm = __int_as_float(cn.y);
        acc.x += nm * tv.x;
        acc.y += nm * tv.y;
        acc.z += nm * tv.z;
        acc.w += nm * tv.w;
    }
    acc.x += __shfl_down(acc.x, 32); acc.y += __shfl_down(acc.y, 32);
    acc.z += __shfl_down(acc.z, 32); acc.w += __shfl_down(acc.w, 32);
    acc.x += __shfl_down(acc.x, 16); acc.y += __shfl_down(acc.y, 16);
    acc.z += __shfl_down(acc.z, 16); acc.w += __shfl_down(acc.w, 16);
    if (lane < 16) {
        float4* op = (float4*)(out + (size_t)node * FD);
        op[fl] = acc;
    }
}

extern "C" void kernel_launch(void* const* d_in, const int* in_sizes, int n_in,
                              void* d_out, int out_size, void* d_ws, size_t ws_size,
                              hipStream_t stream) {
    const float* x  = (const float*)d_in[0];
    const int*   ei = (const int*)d_in[1];
    const float* W1 = (const float*)d_in[2];
    const float* b1 = (const float*)d_in[3];
    const float* W2 = (const float*)d_in[4];
    const float* b2 = (const float*)d_in[5];
    const float* W3 = (const float*)d_in[6];
    const float* b3 = (const float*)d_in[7];
    float* out = (float*)d_out;

    char* ws = (char*)d_ws;
    size_t off = 0;
    float* t        = (float*)(ws + off); off += (size_t)BN * FD * 4;     // 20.48 MB
    int2*  edge_cn  = (int2*)(ws + off);  off += (size_t)TOTE * 8;        // 10.24 MB
    int*   deg      = (int*)(ws + off);   off += (size_t)BN * 4;
    int*   row_start= (int*)(ws + off);   off += (size_t)(BN + 1) * 4;
    float* dinv     = (float*)(ws + off); off += (size_t)BN * 4;
    int*   blocksum = (int*)(ws + off);   off += (size_t)NBLK * 4;
    int*   blockoff = (int*)(ws + off);   off += (size_t)NBLK * 4;
    // rank (5.12 MB) and cnt (5.12 MB) alias t: both are dead before the
    // first k_linear writes t (stream-ordered after k_fill).
    int*   rank     = (int*)t;
    int*   cnt      = (int*)t + (size_t)TOTE;

    const int eb = (TOTE + 255) / 256;      // 5000
    const int ab = (BN * 64 + 255) / 256;   // 20000

    k_count_lds<<<NPA, 256, 0, stream>>>(ei, rank, cnt);
    k_prefix<<<NBLK, 256, 0, stream>>>(cnt, deg, dinv, blocksum);
    k_scanblk<<<1, 64, 0, stream>>>(blocksum, blockoff, row_start);
    k_scan2<<<NBLK, 256, 0, stream>>>(deg, blockoff, row_start);
    k_fill<<<eb, 256, 0, stream>>>(ei, row_start, rank, cnt, dinv, edge_cn);

    // layer 1: t = x@W1^T + b1 ; h1 = agg(t) -> out
    k_linear<0><<<NBLK, 256, 0, stream>>>(x, W1, b1, t);
    k_agg<<<ab, 256, 0, stream>>>(t, row_start, edge_cn, out);
    // layer 2: t = relu(h1)@W2^T + b2 ; h2 = agg(t) -> out
    k_linear<1><<<NBLK, 256, 0, stream>>>(out, W2, b2, t);
    k_agg<<<ab, 256, 0, stream>>>(t, row_start, edge_cn, out);
    // layer 3: t = relu(h2)@W3^T + b3 ; out = agg(t)
    k_linear<1><<<NBLK, 256, 0, stream>>>(out, W3, b3, t);
    k_agg<<<ab, 256, 0, stream>>>(t, row_start, edge_cn, out);
}

// Round 5
// 318.293 us; speedup vs baseline: 1.4526x; 1.0617x over previous
//
#include <hip/hip_runtime.h>
#include <math.h>

#define NB 8
#define NN 10000
#define NE 160000
#define FD 64
#define BN (NB * NN)              // 80000
#define TOTE (NB * NE)            // 1280000
#define NBLK ((BN + 255) / 256)   // 313
#define EPB 10000                 // edges per pass-A block
#define BPG (NE / EPB)            // 16 blocks per graph
#define NPA (NB * BPG)            // 128 pass-A blocks

// ---------- pass A: LDS histogram count + local rank (no global atomics) ----------
__global__ __launch_bounds__(256) void k_count_lds(const int* __restrict__ ei,
                                                   int* __restrict__ rank,
                                                   int* __restrict__ cnt) {
    __shared__ int hist[NN];  // 40 KB
    for (int i = threadIdx.x; i < NN; i += 256) hist[i] = 0;
    __syncthreads();
    int g = blockIdx.x >> 4;        // BPG = 16
    int j = blockIdx.x & 15;
    int base = g * NE + j * EPB;
    for (int i = threadIdx.x; i < EPB; i += 256) {
        int e = base + i;
        int r = ei[2 * e];          // local node id within graph
        rank[e] = atomicAdd(&hist[r], 1);
    }
    __syncthreads();
    int* cp = cnt + (size_t)blockIdx.x * NN;
    for (int i = threadIdx.x; i < NN; i += 256) cp[i] = hist[i];
}

// ---------- pass B: per-row prefix over the 16 block-counts -> deg, dinv, blocksum ----------
__global__ __launch_bounds__(256) void k_prefix(int* __restrict__ cnt,
                                                int* __restrict__ deg,
                                                float* __restrict__ dinv,
                                                int* __restrict__ blocksum) {
    __shared__ int wsum[4];
    int i = blockIdx.x * 256 + threadIdx.x;
    int lane = threadIdx.x & 63;
    int wv = threadIdx.x >> 6;
    int d = 0;
    if (i < BN) {
        int g = i / NN;
        int r = i - g * NN;
        int* cp = cnt + ((size_t)g * BPG) * NN + r;
        int run = 0;
#pragma unroll
        for (int j = 0; j < BPG; j++) {
            int v = cp[(size_t)j * NN];
            cp[(size_t)j * NN] = run;   // exclusive prefix across blocks
            run += v;
        }
        d = run;
        deg[i] = d;
        dinv[i] = (d > 0) ? (1.0f / sqrtf((float)d)) : 0.0f;
    }
    int s = d;
#pragma unroll
    for (int off = 32; off > 0; off >>= 1) s += __shfl_down(s, off);
    if (lane == 0) wsum[wv] = s;
    __syncthreads();
    if (threadIdx.x == 0)
        blocksum[blockIdx.x] = wsum[0] + wsum[1] + wsum[2] + wsum[3];
}

// ---------- 1-wave exclusive scan of 313 block sums ----------
__global__ __launch_bounds__(64) void k_scanblk(const int* __restrict__ blocksum,
                                                int* __restrict__ blockoff,
                                                int* __restrict__ row_start) {
    int lane = threadIdx.x;
    int carry = 0;
    for (int base = 0; base < NBLK; base += 64) {
        int i = base + lane;
        int v = (i < NBLK) ? blocksum[i] : 0;
        int x = v;
#pragma unroll
        for (int off = 1; off < 64; off <<= 1) {
            int y = __shfl_up(x, off);
            if (lane >= off) x += y;
        }
        if (i < NBLK) blockoff[i] = carry + (x - v);
        carry += __shfl(x, 63);
    }
    if (lane == 0) row_start[BN] = carry;
}

// ---------- per-block rescan -> row_start ----------
__global__ __launch_bounds__(256) void k_scan2(const int* __restrict__ deg,
                                               const int* __restrict__ blockoff,
                                               int* __restrict__ row_start) {
    __shared__ int wsum[4];
    int i = blockIdx.x * 256 + threadIdx.x;
    int lane = threadIdx.x & 63;
    int wv = threadIdx.x >> 6;
    int v = (i < BN) ? deg[i] : 0;
    int x = v;
#pragma unroll
    for (int off = 1; off < 64; off <<= 1) {
        int y = __shfl_up(x, off);
        if (lane >= off) x += y;
    }
    if (lane == 63) wsum[wv] = x;
    __syncthreads();
    int add = 0;
    for (int w = 0; w < wv; w++) add += wsum[w];
    if (i < BN) row_start[i] = blockoff[blockIdx.x] + add + (x - v);
}

// ---------- fill CSR: edge_cn[pos] = {col, norm} (atomic-free) ----------
// XCD swizzle: g = blockIdx&7 so graph g's random traffic (cnt/dinv/edge_cn,
// ~2 MB/graph) stays in one XCD's L2 (round-robin dispatch heuristic).
__global__ __launch_bounds__(256) void k_fill(const int* __restrict__ ei,
                                              const int* __restrict__ row_start,
                                              const int* __restrict__ rank,
                                              const int* __restrict__ cnt,
                                              const float* __restrict__ dinv,
                                              int2* __restrict__ edge_cn) {
    int g = blockIdx.x & 7;
    int j = blockIdx.x >> 3;            // 0..624
    int idx = j * 256 + threadIdx.x;    // 0..159999 (exact: 625*256)
    int e = g * NE + idx;
    int jj = idx / EPB;                 // pass-A block within graph
    int rl = ei[2 * e];
    int cl = ei[2 * e + 1];
    int r = g * NN + rl;
    int c = g * NN + cl;
    int pos = row_start[r] + cnt[((size_t)(g * BPG + jj)) * NN + rl] + rank[e];
    float nm = dinv[r] * dinv[c];
    edge_cn[pos] = make_int2(c, __float_as_int(nm));
}

// ---------- linear: t[n][j] = (act(h[n]) @ W^T + b)[j] ----------
// thread-per-row; W transposed in LDS, broadcast float4 reads (conflict-free).
// XCD swizzle: writes graph g's t rows from XCD g so they're L2-resident
// for the following k_agg on the same XCD.
template <int RELU>
__global__ __launch_bounds__(256) void k_linear(const float* __restrict__ hin,
                                                const float* __restrict__ W,
                                                const float* __restrict__ bias,
                                                float* __restrict__ tout) {
    __shared__ __align__(16) float Wt[FD * FD];  // Wt[k*64 + j] = W[j*64 + k]
    __shared__ float bsh[FD];
    for (int idx = threadIdx.x; idx < FD * FD; idx += 256) {
        int j = idx >> 6, k = idx & 63;
        Wt[k * FD + j] = W[idx];
    }
    if (threadIdx.x < FD) bsh[threadIdx.x] = bias[threadIdx.x];
    __syncthreads();

    int g = blockIdx.x & 7;
    int i = blockIdx.x >> 3;                 // 0..39
    int nl = i * 256 + (int)threadIdx.x;     // 0..10239
    if (nl >= NN) return;                    // no further barriers below
    int n = g * NN + nl;

    float acc[FD];
#pragma unroll
    for (int j = 0; j < FD; j++) acc[j] = bsh[j];

    const float4* hp = (const float4*)(hin + (size_t)n * FD);
#pragma unroll
    for (int k4 = 0; k4 < 16; k4++) {
        float4 hv = hp[k4];
        if (RELU) {
            hv.x = fmaxf(hv.x, 0.f);
            hv.y = fmaxf(hv.y, 0.f);
            hv.z = fmaxf(hv.z, 0.f);
            hv.w = fmaxf(hv.w, 0.f);
        }
        float hk[4] = {hv.x, hv.y, hv.z, hv.w};
#pragma unroll
        for (int kk = 0; kk < 4; kk++) {
            const float4* wr = (const float4*)(&Wt[(k4 * 4 + kk) * FD]);
            float h = hk[kk];
#pragma unroll
            for (int j4 = 0; j4 < 16; j4++) {
                float4 w = wr[j4];
                acc[4 * j4 + 0] += h * w.x;
                acc[4 * j4 + 1] += h * w.y;
                acc[4 * j4 + 2] += h * w.z;
                acc[4 * j4 + 3] += h * w.w;
            }
        }
    }
    float4* op = (float4*)(tout + (size_t)n * FD);
#pragma unroll
    for (int j4 = 0; j4 < 16; j4++)
        op[j4] = make_float4(acc[4 * j4], acc[4 * j4 + 1], acc[4 * j4 + 2], acc[4 * j4 + 3]);
}

// ---------- aggregate (pull, CSR): 4 edge slots x 4 deep = 16 edges in flight ----------
// lane = eg(2b)*16 + fl(4b): eg = edge slot, fl = float4 feature group
// XCD swizzle: g = blockIdx&7 -> all gathers for graph g (t slice = 2.56 MB)
// hit one XCD's 4 MB L2 instead of spilling to Infinity Cache.
__global__ __launch_bounds__(256) void k_agg(const float* __restrict__ t,
                                             const int* __restrict__ row_start,
                                             const int2* __restrict__ edge_cn,
                                             float* __restrict__ out) {
    int g = blockIdx.x & 7;
    int i = blockIdx.x >> 3;                          // 0..2499
    int node = g * NN + i * 4 + ((int)threadIdx.x >> 6);  // exact: 2500*4 = NN
    int lane = threadIdx.x & 63;
    int p0 = row_start[node];
    int pe = row_start[node + 1];
    int eg = lane >> 4;
    int fl = lane & 15;
    float4 acc = make_float4(0.f, 0.f, 0.f, 0.f);
    int p = p0 + eg;
    for (; p + 12 < pe; p += 16) {
        int2 cn0 = edge_cn[p];
        int2 cn1 = edge_cn[p + 4];
        int2 cn2 = edge_cn[p + 8];
        int2 cn3 = edge_cn[p + 12];
        float4 t0 = ((const float4*)(t + (size_t)cn0.x * FD))[fl];
        float4 t1 = ((const float4*)(t + (size_t)cn1.x * FD))[fl];
        float4 t2 = ((const float4*)(t + (size_t)cn2.x * FD))[fl];
        float4 t3 = ((const float4*)(t + (size_t)cn3.x * FD))[fl];
        float n0 = __int_as_float(cn0.y), n1 = __int_as_float(cn1.y);
        float n2 = __int_as_float(cn2.y), n3 = __int_as_float(cn3.y);
        acc.x += n0 * t0.x + n1 * t1.x + n2 * t2.x + n3 * t3.x;
        acc.y += n0 * t0.y + n1 * t1.y + n2 * t2.y + n3 * t3.y;
        acc.z += n0 * t0.z + n1 * t1.z + n2 * t2.z + n3 * t3.z;
        acc.w += n0 * t0.w + n1 * t1.w + n2 * t2.w + n3 * t3.w;
    }
    for (; p < pe; p += 4) {
        int2 cn = edge_cn[p];
        float4 tv = ((const float4*)(t + (size_t)cn.x * FD))[fl];
        float nm = __int_as_float(cn.y);
        acc.x += nm * tv.x;
        acc.y += nm * tv.y;
        acc.z += nm * tv.z;
        acc.w += nm * tv.w;
    }
    acc.x += __shfl_down(acc.x, 32); acc.y += __shfl_down(acc.y, 32);
    acc.z += __shfl_down(acc.z, 32); acc.w += __shfl_down(acc.w, 32);
    acc.x += __shfl_down(acc.x, 16); acc.y += __shfl_down(acc.y, 16);
    acc.z += __shfl_down(acc.z, 16); acc.w += __shfl_down(acc.w, 16);
    if (lane < 16) {
        float4* op = (float4*)(out + (size_t)node * FD);
        op[fl] = acc;
    }
}

extern "C" void kernel_launch(void* const* d_in, const int* in_sizes, int n_in,
                              void* d_out, int out_size, void* d_ws, size_t ws_size,
                              hipStream_t stream) {
    const float* x  = (const float*)d_in[0];
    const int*   ei = (const int*)d_in[1];
    const float* W1 = (const float*)d_in[2];
    const float* b1 = (const float*)d_in[3];
    const float* W2 = (const float*)d_in[4];
    const float* b2 = (const float*)d_in[5];
    const float* W3 = (const float*)d_in[6];
    const float* b3 = (const float*)d_in[7];
    float* out = (float*)d_out;

    char* ws = (char*)d_ws;
    size_t off = 0;
    float* t        = (float*)(ws + off); off += (size_t)BN * FD * 4;     // 20.48 MB
    int2*  edge_cn  = (int2*)(ws + off);  off += (size_t)TOTE * 8;        // 10.24 MB
    int*   deg      = (int*)(ws + off);   off += (size_t)BN * 4;
    int*   row_start= (int*)(ws + off);   off += (size_t)(BN + 1) * 4;
    float* dinv     = (float*)(ws + off); off += (size_t)BN * 4;
    int*   blocksum = (int*)(ws + off);   off += (size_t)NBLK * 4;
    int*   blockoff = (int*)(ws + off);   off += (size_t)NBLK * 4;
    // rank (5.12 MB) and cnt (5.12 MB) alias t: both are dead before the
    // first k_linear writes t (stream-ordered after k_fill).
    int*   rank     = (int*)t;
    int*   cnt      = (int*)t + (size_t)TOTE;

    const int fb = NB * (NE / 256);         // 5000 (exact)
    const int lb = NB * 40;                 // 320 (40 blocks x 256 rows per graph)
    const int ab = NB * (NN / 4);           // 20000 (exact)

    k_count_lds<<<NPA, 256, 0, stream>>>(ei, rank, cnt);
    k_prefix<<<NBLK, 256, 0, stream>>>(cnt, deg, dinv, blocksum);
    k_scanblk<<<1, 64, 0, stream>>>(blocksum, blockoff, row_start);
    k_scan2<<<NBLK, 256, 0, stream>>>(deg, blockoff, row_start);
    k_fill<<<fb, 256, 0, stream>>>(ei, row_start, rank, cnt, dinv, edge_cn);

    // layer 1: t = x@W1^T + b1 ; h1 = agg(t) -> out
    k_linear<0><<<lb, 256, 0, stream>>>(x, W1, b1, t);
    k_agg<<<ab, 256, 0, stream>>>(t, row_start, edge_cn, out);
    // layer 2: t = relu(h1)@W2^T + b2 ; h2 = agg(t) -> out
    k_linear<1><<<lb, 256, 0, stream>>>(out, W2, b2, t);
    k_agg<<<ab, 256, 0, stream>>>(t, row_start, edge_cn, out);
    // layer 3: t = relu(h2)@W3^T + b3 ; out = agg(t)
    k_linear<1><<<lb, 256, 0, stream>>>(out, W3, b3, t);
    k_agg<<<ab, 256, 0, stream>>>(t, row_start, edge_cn, out);
}